// Round 17
// baseline (228.688 us; speedup 1.0000x reference)
//
#include <hip/hip_runtime.h>
#include <hip/hip_bf16.h>

// ---- problem constants ----
#define HD 128          // head dim == hidden dim
#define NH 8            // heads
#define SQ 2048         // seq len
#define NROWS 4096      // B*S
#define QSCALE 0.06375871607f   // rsqrt(128)*0.5*log2(e): QK^T MFMA emits c = score*0.5*log2e

typedef __bf16 bf16;
typedef bf16 bf16x8 __attribute__((ext_vector_type(8)));
typedef float f32x4 __attribute__((ext_vector_type(4)));

__device__ __forceinline__ f32x4 mfma16(bf16x8 a, bf16x8 b, f32x4 c) {
  return __builtin_amdgcn_mfma_f32_16x16x32_bf16(a, b, c, 0, 0, 0);
}
__device__ __forceinline__ bf16x8 ld8(const bf16* p) { return *(const bf16x8*)p; }
__device__ __forceinline__ unsigned short bfu(float v) {
  return __builtin_bit_cast(unsigned short, (bf16)v);
}
__device__ __forceinline__ unsigned packbf2(float a, float b) {
  return (unsigned)bfu(a) | ((unsigned)bfu(b) << 16);
}
// async global->LDS, 16B/lane; LDS dest = wave-uniform base (+lane*16 implicit);
// global src is per-lane (pre-swizzle the source to realize swizzled LDS layouts).
__device__ __forceinline__ void gload_lds16(const void* g, void* l) {
  __builtin_amdgcn_global_load_lds(
      (const __attribute__((address_space(1))) void*)g,
      (__attribute__((address_space(3))) void*)l, 16, 0, 0);
}

// ---------------- prep: x->bf16, adj->u8 ----------------
__global__ void k_prep_a(const float* __restrict__ x, const int* __restrict__ adj,
                         bf16* __restrict__ xb, unsigned char* __restrict__ mask8) {
  int idx = blockIdx.x * 256 + threadIdx.x;
  if (idx < NROWS * HD) { xb[idx] = (bf16)x[idx]; return; }
  int j = idx - NROWS * HD;
  if (j < (SQ * SQ / 4)) {
    int4 a = ((const int4*)adj)[j];
    uchar4 m;
    m.x = (unsigned char)a.x; m.y = (unsigned char)a.y;
    m.z = (unsigned char)a.z; m.w = (unsigned char)a.w;
    ((uchar4*)mask8)[j] = m;
  }
}

// ---------------- prep: weights -> bf16, [n][k] layout ----------------
__global__ void k_prep_w(const float* __restrict__ Wq, const float* __restrict__ Wk,
                         const float* __restrict__ Wv, const float* __restrict__ Wo,
                         const float* __restrict__ W1, const float* __restrict__ W2,
                         bf16* __restrict__ WqkvT, bf16* __restrict__ WoT,
                         bf16* __restrict__ W1T, bf16* __restrict__ W2T) {
  int idx = blockIdx.x * 256 + threadIdx.x;
  if (idx < 3072 * 128) {
    int n = idx >> 7, kk = idx & 127;
    int sel = n >> 10, nn = n & 1023;
    const float* W = (sel == 0) ? Wq : (sel == 1 ? Wk : Wv);
    WqkvT[idx] = (bf16)W[kk * 1024 + nn];
    return;
  }
  int j = idx - 3072 * 128;
  if (j < 128 * 1024) { int n = j >> 10, kk = j & 1023; WoT[j] = (bf16)Wo[kk * 128 + n]; return; }
  j -= 128 * 1024;
  if (j < 16384) { int n = j >> 7, kk = j & 127; W1T[j] = (bf16)W1[kk * 128 + n]; return; }
  j -= 16384;
  if (j < 16384) { int n = j >> 7, kk = j & 127; W2T[j] = (bf16)W2[kk * 128 + n]; return; }
}

// ---------------- QKV projection GEMM: (4096x128)@(128x3072) ----------------
// q,k written [b][h][s][d] (q pre-scaled by QSCALE); v written transposed [b][h][d][s].
__global__ __launch_bounds__(256, 4) void k_qkv(
    const bf16* __restrict__ xb, const bf16* __restrict__ WqkvT,
    const float* __restrict__ bq, const float* __restrict__ bk, const float* __restrict__ bv,
    bf16* __restrict__ qT, bf16* __restrict__ kT, bf16* __restrict__ vT) {
  const int bid = blockIdx.x;
  const int m0 = (bid & 63) << 6;
  const int n0 = (bid >> 6) << 6;
  const int tid = threadIdx.x;
  const int w = tid >> 6, lane = tid & 63, lo = lane & 15, hi = lane >> 4;
  const int mw = m0 + ((w >> 1) << 5);
  const int nw = n0 + ((w & 1) << 5);
  bf16x8 av[2][4], bw[2][4];
#pragma unroll
  for (int ms = 0; ms < 2; ++ms)
#pragma unroll
    for (int ks = 0; ks < 4; ++ks)
      av[ms][ks] = ld8(xb + (size_t)(mw + ms * 16 + lo) * 128 + ks * 32 + hi * 8);
#pragma unroll
  for (int ns = 0; ns < 2; ++ns)
#pragma unroll
    for (int ks = 0; ks < 4; ++ks)
      bw[ns][ks] = ld8(WqkvT + (size_t)(nw + ns * 16 + lo) * 128 + ks * 32 + hi * 8);
  const f32x4 z4 = {0.f, 0.f, 0.f, 0.f};
  f32x4 acc[2][2] = {{z4, z4}, {z4, z4}};
#pragma unroll
  for (int ms = 0; ms < 2; ++ms)
#pragma unroll
    for (int ns = 0; ns < 2; ++ns)
#pragma unroll
      for (int ks = 0; ks < 4; ++ks)
        acc[ms][ns] = mfma16(av[ms][ks], bw[ns][ks], acc[ms][ns]);
#pragma unroll
  for (int ns = 0; ns < 2; ++ns) {
    const int n = nw + ns * 16 + lo;
    const int sel = n >> 10, nn = n & 1023;
    const float bia = (sel == 0 ? bq : sel == 1 ? bk : bv)[nn];
    const int hh = nn >> 7, d = nn & 127;
#pragma unroll
    for (int ms = 0; ms < 2; ++ms) {
      const int mb = mw + ms * 16 + hi * 4;
      const int bb = mb >> 11, s = mb & 2047;
      if (sel == 0) {
#pragma unroll
        for (int r = 0; r < 4; ++r)
          qT[(size_t)((bb * 8 + hh) * 2048 + s + r) * 128 + d] =
              (bf16)((acc[ms][ns][r] + bia) * QSCALE);
      } else if (sel == 1) {
#pragma unroll
        for (int r = 0; r < 4; ++r)
          kT[(size_t)((bb * 8 + hh) * 2048 + s + r) * 128 + d] = (bf16)(acc[ms][ns][r] + bia);
      } else {
        ushort4 pk;
        pk.x = bfu(acc[ms][ns][0] + bia);
        pk.y = bfu(acc[ms][ns][1] + bia);
        pk.z = bfu(acc[ms][ns][2] + bia);
        pk.w = bfu(acc[ms][ns][3] + bia);
        *(ushort4*)(vT + (size_t)((bb * 8 + hh) * 128 + d) * 2048 + s) = pk;
      }
    }
  }
}

// ---------------- fused attention (v15: r13 structure re-tiled to 4 barrier domains/CU) --
// grid 1024 = 16 (b,h) x 64 q-blocks of 32 rows; 128 threads = 2 waves; wave w owns q rows
// [q0+w*16,+16) over ALL 2048 kv. Per 32-kv chunk the block stages K(8KB, XOR-swizzled via
// pre-swizzled source)+V(8KB) via global_load_lds (dbuf, 4+4 loads/wave). LDS 34.9KB ->
// 4 blocks/CU = 4 INDEPENDENT barrier domains (r13 had 2) at the same 8 waves/CU and the
// same per-wave LDS read volume. exp: c pre-scaled by 0.5*log2e -> p=exp2(fma(c,m,c));
// sweep2 folds normalization into the exponent (c + lr). setprio(1) around PV MFMAs.
__global__ __launch_bounds__(128, 2) void k_attn(
    const bf16* __restrict__ qT, const bf16* __restrict__ kT,
    const bf16* __restrict__ vT, const unsigned char* __restrict__ mask8,
    float* __restrict__ attn_out, bf16* __restrict__ Oc) {
  __shared__ __align__(16) char kbuf[2][8192];
  __shared__ __align__(16) char vbuf[2][8192];
  __shared__ __align__(16) char stash[2][1024];
  __shared__ float red2[32];

  // XCD-aware bijective swizzle: XCD x gets 128 consecutive works = exactly 2 (b,h) pairs.
  const int lbid = blockIdx.x;
  const int work = ((lbid & 7) << 7) + (lbid >> 3);
  const int bh = work >> 6;
  const int q0 = (work & 63) << 5;
  const int b = bh >> 3, h = bh & 7;
  const int tid = threadIdx.x;
  const int w = tid >> 6, lane = tid & 63, lo = lane & 15, hi = lane >> 4;

  const bf16* Qh = qT + (size_t)bh * SQ * HD;
  const bf16* Kh = kT + (size_t)bh * SQ * HD;
  const bf16* Vh = vT + (size_t)bh * HD * SQ;
  const int qg = q0 + w * 16 + lo;           // this lane's q row (col of swapped QK^T)

  // staging source addresses. K phys LDS (row,s) holds logical slot s^(row&7).
  // Wave w stages K rows [w*16,+16) (4 loads of 4 rows) and V d-rows [w*64,+64) (4 of 16).
  const int rit = lane >> 4;                                    // row-in-load 0..3
  const bf16* kgA = Kh + (size_t)(w * 16 + rit) * HD + (((lane & 15) ^ rit) << 3);        // j=0,2
  const bf16* kgB = Kh + (size_t)(w * 16 + rit) * HD + (((lane & 15) ^ (4 + rit)) << 3);  // j=1,3
  const bf16* vg  = Vh + (size_t)(w * 64 + (lane >> 2)) * SQ + ((lane & 3) << 3);
  char* kdst = (char*)0;  // computed per call below
  auto stageK = [&](char* kb, int kvbase) {
    char* base = kb + w * 4096;
    gload_lds16(kgA + (size_t)(kvbase + 0) * HD,  base + 0 * 1024);
    gload_lds16(kgB + (size_t)(kvbase + 4) * HD,  base + 1 * 1024);
    gload_lds16(kgA + (size_t)(kvbase + 8) * HD,  base + 2 * 1024);
    gload_lds16(kgB + (size_t)(kvbase + 12) * HD, base + 3 * 1024);
  };
  auto stageV = [&](char* vb, int kvbase) {
    char* base = vb + w * 4096;
    gload_lds16(vg + (size_t)(0 * 16) * SQ + kvbase, base + 0 * 1024);
    gload_lds16(vg + (size_t)(1 * 16) * SQ + kvbase, base + 1 * 1024);
    gload_lds16(vg + (size_t)(2 * 16) * SQ + kvbase, base + 2 * 1024);
    gload_lds16(vg + (size_t)(3 * 16) * SQ + kvbase, base + 3 * 1024);
  };

  bf16x8 qf[4];                              // 16 q rows (pre-scaled by QSCALE)
#pragma unroll
  for (int ks = 0; ks < 4; ++ks)
    qf[ks] = ld8(Qh + (size_t)qg * HD + ks * 32 + hi * 8);

  const f32x4 z4 = {0.f, 0.f, 0.f, 0.f};
  f32x4 acc[8];
#pragma unroll
  for (int ds = 0; ds < 8; ++ds) acc[ds] = z4;
  float ssum = 0.f;

  // ======== sweep 1: sums + PV ========
  stageK(kbuf[0], 0);
  stageV(vbuf[0], 0);
  __syncthreads();

  for (int i = 0; i < 64; ++i) {
    const int kvA = i << 5;
    const int cur = i & 1;
    if (i < 63) {
      stageK(kbuf[cur ^ 1], kvA + 32);
      stageV(vbuf[cur ^ 1], kvA + 32);
    }
    const char* kb = kbuf[cur];
    const char* vb = vbuf[cur];
#pragma unroll
    for (int t = 0; t < 2; ++t) {
      const int row = t * 16 + lo;
      bf16x8 af[4];
#pragma unroll
      for (int ks = 0; ks < 4; ++ks)
        af[ks] = *(const bf16x8*)(kb + row * 256 + ((((ks << 2) + hi)) ^ (row & 7)) * 16);
      f32x4 c = z4;
#pragma unroll
      for (int ks = 0; ks < 4; ++ks) c = mfma16(af[ks], qf[ks], c);
      const unsigned mu = *(const unsigned*)(mask8 + (size_t)qg * SQ + kvA + t * 16 + hi * 4);
      // p = exp2(c*(1+m)), c pre-scaled by 0.5*log2e; m in {0,1}
      float p0 = exp2f(fmaf(c[0], (float)(mu & 0xff),         c[0]));
      float p1 = exp2f(fmaf(c[1], (float)((mu >> 8) & 0xff),  c[1]));
      float p2 = exp2f(fmaf(c[2], (float)((mu >> 16) & 0xff), c[2]));
      float p3 = exp2f(fmaf(c[3], (float)((mu >> 24) & 0xff), c[3]));
      ssum += (p0 + p1) + (p2 + p3);
      *(uint2*)(stash[w] + lo * 64 + ((t * 32 + hi * 8) ^ ((lo & 3) << 4))) =
          make_uint2(packbf2(p0, p1), packbf2(p2, p3));
    }
    // PV over these 32 kv (same-wave stash readback)
    bf16x8 pa = *(const bf16x8*)(stash[w] + lo * 64 + ((hi * 16) ^ ((lo & 3) << 4)));
    __builtin_amdgcn_s_setprio(1);
#pragma unroll
    for (int ds = 0; ds < 8; ++ds) {
      bf16x8 vf = *(const bf16x8*)(vb + (ds * 16 + lo) * 64 + hi * 16);
      acc[ds] = mfma16(pa, vf, acc[ds]);
    }
    __builtin_amdgcn_s_setprio(0);
    __syncthreads();
  }

  // row sums complete per wave (wave saw full kv): reduce over hi, publish 1/sum
  ssum += __shfl_xor(ssum, 16);
  ssum += __shfl_xor(ssum, 32);
  if (hi == 0) red2[w * 16 + lo] = 1.0f / ssum;
  __syncthreads();

  // O write: normalized, direct from regs (no cross-wave reduce needed)
#pragma unroll
  for (int ds = 0; ds < 8; ++ds)
#pragma unroll
    for (int r = 0; r < 4; ++r) {
      const int qrow = w * 16 + hi * 4 + r;
      Oc[(size_t)(b * SQ + q0 + qrow) * (NH * HD) + h * HD + ds * 16 + lo] =
          (bf16)(acc[ds][r] * red2[qrow]);
    }

  // ======== sweep 2: recompute QK^T from staged K, write normalized attn ========
  const float lr = log2f(red2[w * 16 + lo]); // fold normalization into the exponent
  float* abase = attn_out + (size_t)bh * SQ * SQ + (size_t)qg * SQ;
  stageK(kbuf[0], 0);
  __syncthreads();
  for (int i = 0; i < 64; ++i) {
    const int kvA = i << 5;
    const int cur = i & 1;
    if (i < 63) stageK(kbuf[cur ^ 1], kvA + 32);
    const char* kb = kbuf[cur];
#pragma unroll
    for (int t = 0; t < 2; ++t) {
      const int row = t * 16 + lo;
      bf16x8 af[4];
#pragma unroll
      for (int ks = 0; ks < 4; ++ks)
        af[ks] = *(const bf16x8*)(kb + row * 256 + ((((ks << 2) + hi)) ^ (row & 7)) * 16);
      f32x4 c = z4;
#pragma unroll
      for (int ks = 0; ks < 4; ++ks) c = mfma16(af[ks], qf[ks], c);
      const unsigned mu = *(const unsigned*)(mask8 + (size_t)qg * SQ + kvA + t * 16 + hi * 4);
      f32x4 o;
      o[0] = exp2f(fmaf(c[0], (float)(mu & 0xff),         c[0] + lr));
      o[1] = exp2f(fmaf(c[1], (float)((mu >> 8) & 0xff),  c[1] + lr));
      o[2] = exp2f(fmaf(c[2], (float)((mu >> 16) & 0xff), c[2] + lr));
      o[3] = exp2f(fmaf(c[3], (float)((mu >> 24) & 0xff), c[3] + lr));
      __builtin_nontemporal_store(o, (f32x4*)(abase + kvA + t * 16 + hi * 4));
    }
    __syncthreads();
  }
}

// ---------------- out@Wo + bo + x -> LayerNorm1 -> h (f32 + bf16) ----------------
__global__ __launch_bounds__(256, 4) void k_owo(
    const bf16* __restrict__ Oc, const bf16* __restrict__ WoT,
    const float* __restrict__ bo, const float* __restrict__ x,
    const float* __restrict__ g1, const float* __restrict__ be1,
    float* __restrict__ hf, bf16* __restrict__ hb) {
  __shared__ __align__(16) float hbuf[16 * 128];
  const int m0 = blockIdx.x * 16;
  const int tid = threadIdx.x;
  const int w = tid >> 6, lane = tid & 63, lo = lane & 15, hi = lane >> 4;
  const int nw = w * 32;
  const f32x4 z4 = {0.f, 0.f, 0.f, 0.f};
  f32x4 acc[2] = {z4, z4};
#pragma unroll 4
  for (int kk = 0; kk < 32; ++kk) {
    bf16x8 a = ld8(Oc + (size_t)(m0 + lo) * 1024 + kk * 32 + hi * 8);
#pragma unroll
    for (int ns = 0; ns < 2; ++ns) {
      bf16x8 bb = ld8(WoT + (size_t)(nw + ns * 16 + lo) * 1024 + kk * 32 + hi * 8);
      acc[ns] = mfma16(a, bb, acc[ns]);
    }
  }
#pragma unroll
  for (int ns = 0; ns < 2; ++ns) {
    const int n = nw + ns * 16 + lo;
    const float bia = bo[n];
#pragma unroll
    for (int r = 0; r < 4; ++r) {
      const int mr = hi * 4 + r;
      hbuf[mr * 128 + n] = acc[ns][r] + bia + x[(size_t)(m0 + mr) * 128 + n];
    }
  }
  __syncthreads();
  const float2 g = *(const float2*)(g1 + lane * 2);
  const float2 be = *(const float2*)(be1 + lane * 2);
#pragma unroll
  for (int rr = 0; rr < 4; ++rr) {
    const int row = w * 4 + rr;
    float2 v = *(float2*)&hbuf[row * 128 + lane * 2];
    float s = v.x + v.y, sq = v.x * v.x + v.y * v.y;
#pragma unroll
    for (int off = 32; off; off >>= 1) { s += __shfl_xor(s, off); sq += __shfl_xor(sq, off); }
    const float mean = s * (1.f / 128.f);
    const float var = sq * (1.f / 128.f) - mean * mean;
    const float rstd = rsqrtf(var + 1e-5f);
    const float y0 = (v.x - mean) * rstd * g.x + be.x;
    const float y1 = (v.y - mean) * rstd * g.y + be.y;
    const size_t o = (size_t)(m0 + row) * 128 + lane * 2;
    *(float2*)(hf + o) = make_float2(y0, y1);
    *(unsigned*)(hb + o) = packbf2(y0, y1);
  }
}

// ---------------- FFN (relu(h@W1+b1)@W2+b2) + residual -> LayerNorm2 -> y ----------------
__global__ __launch_bounds__(256, 4) void k_ffn(
    const bf16* __restrict__ hb, const float* __restrict__ hf,
    const bf16* __restrict__ W1T, const bf16* __restrict__ W2T,
    const float* __restrict__ b1, const float* __restrict__ b2,
    const float* __restrict__ g2, const float* __restrict__ be2,
    float* __restrict__ yout) {
  __shared__ __align__(16) bf16 s1[16 * 136];   // +8 pad per row: conflict-free b128 rereads
  __shared__ __align__(16) float ybuf[16 * 128];
  const int m0 = blockIdx.x * 16;
  const int tid = threadIdx.x;
  const int w = tid >> 6, lane = tid & 63, lo = lane & 15, hi = lane >> 4;
  const int nw = w * 32;
  const f32x4 z4 = {0.f, 0.f, 0.f, 0.f};
  f32x4 a1[2] = {z4, z4};
#pragma unroll
  for (int kk = 0; kk < 4; ++kk) {
    bf16x8 a = ld8(hb + (size_t)(m0 + lo) * 128 + kk * 32 + hi * 8);
#pragma unroll
    for (int ns = 0; ns < 2; ++ns)
      a1[ns] = mfma16(a, ld8(W1T + (size_t)(nw + ns * 16 + lo) * 128 + kk * 32 + hi * 8), a1[ns]);
  }
#pragma unroll
  for (int ns = 0; ns < 2; ++ns) {
    const int n = nw + ns * 16 + lo;
    const float bia = b1[n];
#pragma unroll
    for (int r = 0; r < 4; ++r)
      s1[(hi * 4 + r) * 136 + n] = (bf16)fmaxf(a1[ns][r] + bia, 0.f);
  }
  __syncthreads();
  f32x4 a2[2] = {z4, z4};
#pragma unroll
  for (int kk = 0; kk < 4; ++kk) {
    bf16x8 a = *(const bf16x8*)&s1[lo * 136 + kk * 32 + hi * 8];
#pragma unroll
    for (int ns = 0; ns < 2; ++ns)
      a2[ns] = mfma16(a, ld8(W2T + (size_t)(nw + ns * 16 + lo) * 128 + kk * 32 + hi * 8), a2[ns]);
  }
#pragma unroll
  for (int ns = 0; ns < 2; ++ns) {
    const int n = nw + ns * 16 + lo;
    const float bia = b2[n];
#pragma unroll
    for (int r = 0; r < 4; ++r) {
      const int mr = hi * 4 + r;
      ybuf[mr * 128 + n] = a2[ns][r] + bia + hf[(size_t)(m0 + mr) * 128 + n];
    }
  }
  __syncthreads();
  const float2 g = *(const float2*)(g2 + lane * 2);
  const float2 be = *(const float2*)(be2 + lane * 2);
#pragma unroll
  for (int rr = 0; rr < 4; ++rr) {
    const int row = w * 4 + rr;
    float2 v = *(float2*)&ybuf[row * 128 + lane * 2];
    float s = v.x + v.y, sq = v.x * v.x + v.y * v.y;
#pragma unroll
    for (int off = 32; off; off >>= 1) { s += __shfl_xor(s, off); sq += __shfl_xor(sq, off); }
    const float mean = s * (1.f / 128.f);
    const float var = sq * (1.f / 128.f) - mean * mean;
    const float rstd = rsqrtf(var + 1e-5f);
    const float y0 = (v.x - mean) * rstd * g.x + be.x;
    const float y1 = (v.y - mean) * rstd * g.y + be.y;
    *(float2*)(yout + (size_t)(m0 + row) * 128 + lane * 2) = make_float2(y0, y1);
  }
}

extern "C" void kernel_launch(void* const* d_in, const int* in_sizes, int n_in,
                              void* d_out, int out_size, void* d_ws, size_t ws_size,
                              hipStream_t stream) {
  const float* x  = (const float*)d_in[0];
  const int* adj  = (const int*)d_in[1];
  const float* Wq = (const float*)d_in[2];  const float* bq = (const float*)d_in[3];
  const float* Wk = (const float*)d_in[4];  const float* bk = (const float*)d_in[5];
  const float* Wv = (const float*)d_in[6];  const float* bv = (const float*)d_in[7];
  const float* Wo = (const float*)d_in[8];  const float* bo = (const float*)d_in[9];
  const float* g1 = (const float*)d_in[10]; const float* be1 = (const float*)d_in[11];
  const float* g2 = (const float*)d_in[12]; const float* be2 = (const float*)d_in[13];
  const float* W1 = (const float*)d_in[14]; const float* b1 = (const float*)d_in[15];
  const float* W2 = (const float*)d_in[16]; const float* b2 = (const float*)d_in[17];

  char* ws = (char*)d_ws;
  bf16* xb     = (bf16*)(ws + 0);
  bf16* WqkvT  = (bf16*)(ws + 1048576);
  bf16* WoT    = (bf16*)(ws + 1835008);
  bf16* W1T    = (bf16*)(ws + 2097152);
  bf16* W2T    = (bf16*)(ws + 2129920);
  unsigned char* mask8 = (unsigned char*)(ws + 2162688);
  bf16* qT     = (bf16*)(ws + 6356992);
  bf16* kT     = (bf16*)(ws + 14745600);
  bf16* vT     = (bf16*)(ws + 23134208);
  bf16* Oc     = (bf16*)(ws + 31522816);
  float* hf    = (float*)(ws + 39911424);
  bf16* hb     = (bf16*)(ws + 42008576);

  float* yout = (float*)d_out;
  float* attn_out = yout + (size_t)NROWS * HD;  // y first (524288 f32), then attn

  k_prep_a<<<6144, 256, 0, stream>>>(x, adj, xb, mask8);
  k_prep_w<<<2176, 256, 0, stream>>>(Wq, Wk, Wv, Wo, W1, W2, WqkvT, WoT, W1T, W2T);
  k_qkv<<<3072, 256, 0, stream>>>(xb, WqkvT, bq, bk, bv, qT, kT, vT);
  k_attn<<<1024, 128, 0, stream>>>(qT, kT, vT, mask8, attn_out, Oc);
  k_owo<<<256, 256, 0, stream>>>(Oc, WoT, bo, x, g1, be1, hf, hb);
  k_ffn<<<256, 256, 0, stream>>>(hb, hf, W1T, W2T, b1, b2, g2, be2, yout);
}

// Round 18
// 209.829 us; speedup vs baseline: 1.0899x; 1.0899x over previous
//
#include <hip/hip_runtime.h>
#include <hip/hip_bf16.h>

// ---- problem constants ----
#define HD 128          // head dim == hidden dim
#define NH 8            // heads
#define SQ 2048         // seq len
#define NROWS 4096      // B*S
#define RSQRT_D 0.08838834764831845f
#define L2EH 0.72134752044f   // 0.5 * log2(e)

typedef __bf16 bf16;
typedef bf16 bf16x8 __attribute__((ext_vector_type(8)));
typedef float f32x4 __attribute__((ext_vector_type(4)));

__device__ __forceinline__ f32x4 mfma16(bf16x8 a, bf16x8 b, f32x4 c) {
  return __builtin_amdgcn_mfma_f32_16x16x32_bf16(a, b, c, 0, 0, 0);
}
__device__ __forceinline__ bf16x8 ld8(const bf16* p) { return *(const bf16x8*)p; }
__device__ __forceinline__ unsigned short bfu(float v) {
  return __builtin_bit_cast(unsigned short, (bf16)v);
}
__device__ __forceinline__ unsigned packbf2(float a, float b) {
  return (unsigned)bfu(a) | ((unsigned)bfu(b) << 16);
}
// async global->LDS, 16B/lane; LDS dest = uniform base + lane*16 (linear);
// global src is PER-LANE (pre-swizzle the source to realize swizzled LDS layouts).
__device__ __forceinline__ void gload_lds16(const void* g, void* l) {
  __builtin_amdgcn_global_load_lds(
      (const __attribute__((address_space(1))) void*)g,
      (__attribute__((address_space(3))) void*)l, 16, 0, 0);
}

// ---------------- prep: x->bf16, adj->u8 ----------------
__global__ void k_prep_a(const float* __restrict__ x, const int* __restrict__ adj,
                         bf16* __restrict__ xb, unsigned char* __restrict__ mask8) {
  int idx = blockIdx.x * 256 + threadIdx.x;
  if (idx < NROWS * HD) { xb[idx] = (bf16)x[idx]; return; }
  int j = idx - NROWS * HD;
  if (j < (SQ * SQ / 4)) {
    int4 a = ((const int4*)adj)[j];
    uchar4 m;
    m.x = (unsigned char)a.x; m.y = (unsigned char)a.y;
    m.z = (unsigned char)a.z; m.w = (unsigned char)a.w;
    ((uchar4*)mask8)[j] = m;
  }
}

// ---------------- prep: weights -> bf16, [n][k] layout ----------------
__global__ void k_prep_w(const float* __restrict__ Wq, const float* __restrict__ Wk,
                         const float* __restrict__ Wv, const float* __restrict__ Wo,
                         const float* __restrict__ W1, const float* __restrict__ W2,
                         bf16* __restrict__ WqkvT, bf16* __restrict__ WoT,
                         bf16* __restrict__ W1T, bf16* __restrict__ W2T) {
  int idx = blockIdx.x * 256 + threadIdx.x;
  if (idx < 3072 * 128) {
    int n = idx >> 7, kk = idx & 127;
    int sel = n >> 10, nn = n & 1023;
    const float* W = (sel == 0) ? Wq : (sel == 1 ? Wk : Wv);
    WqkvT[idx] = (bf16)W[kk * 1024 + nn];
    return;
  }
  int j = idx - 3072 * 128;
  if (j < 128 * 1024) { int n = j >> 10, kk = j & 1023; WoT[j] = (bf16)Wo[kk * 128 + n]; return; }
  j -= 128 * 1024;
  if (j < 16384) { int n = j >> 7, kk = j & 127; W1T[j] = (bf16)W1[kk * 128 + n]; return; }
  j -= 16384;
  if (j < 16384) { int n = j >> 7, kk = j & 127; W2T[j] = (bf16)W2[kk * 128 + n]; return; }
}

// ---------------- QKV projection GEMM: (4096x128)@(128x3072) ----------------
// q,k written [b][h][s][d] (q pre-scaled by 1/sqrt(D)); v written transposed [b][h][d][s].
__global__ __launch_bounds__(256, 4) void k_qkv(
    const bf16* __restrict__ xb, const bf16* __restrict__ WqkvT,
    const float* __restrict__ bq, const float* __restrict__ bk, const float* __restrict__ bv,
    bf16* __restrict__ qT, bf16* __restrict__ kT, bf16* __restrict__ vT) {
  const int bid = blockIdx.x;
  const int m0 = (bid & 63) << 6;
  const int n0 = (bid >> 6) << 6;
  const int tid = threadIdx.x;
  const int w = tid >> 6, lane = tid & 63, lo = lane & 15, hi = lane >> 4;
  const int mw = m0 + ((w >> 1) << 5);
  const int nw = n0 + ((w & 1) << 5);
  bf16x8 av[2][4], bw[2][4];
#pragma unroll
  for (int ms = 0; ms < 2; ++ms)
#pragma unroll
    for (int ks = 0; ks < 4; ++ks)
      av[ms][ks] = ld8(xb + (size_t)(mw + ms * 16 + lo) * 128 + ks * 32 + hi * 8);
#pragma unroll
  for (int ns = 0; ns < 2; ++ns)
#pragma unroll
    for (int ks = 0; ks < 4; ++ks)
      bw[ns][ks] = ld8(WqkvT + (size_t)(nw + ns * 16 + lo) * 128 + ks * 32 + hi * 8);
  const f32x4 z4 = {0.f, 0.f, 0.f, 0.f};
  f32x4 acc[2][2] = {{z4, z4}, {z4, z4}};
#pragma unroll
  for (int ms = 0; ms < 2; ++ms)
#pragma unroll
    for (int ns = 0; ns < 2; ++ns)
#pragma unroll
      for (int ks = 0; ks < 4; ++ks)
        acc[ms][ns] = mfma16(av[ms][ks], bw[ns][ks], acc[ms][ns]);
#pragma unroll
  for (int ns = 0; ns < 2; ++ns) {
    const int n = nw + ns * 16 + lo;
    const int sel = n >> 10, nn = n & 1023;
    const float bia = (sel == 0 ? bq : sel == 1 ? bk : bv)[nn];
    const int hh = nn >> 7, d = nn & 127;
#pragma unroll
    for (int ms = 0; ms < 2; ++ms) {
      const int mb = mw + ms * 16 + hi * 4;
      const int bb = mb >> 11, s = mb & 2047;
      if (sel == 0) {
#pragma unroll
        for (int r = 0; r < 4; ++r)
          qT[(size_t)((bb * 8 + hh) * 2048 + s + r) * 128 + d] =
              (bf16)((acc[ms][ns][r] + bia) * RSQRT_D);
      } else if (sel == 1) {
#pragma unroll
        for (int r = 0; r < 4; ++r)
          kT[(size_t)((bb * 8 + hh) * 2048 + s + r) * 128 + d] = (bf16)(acc[ms][ns][r] + bia);
      } else {
        ushort4 pk;
        pk.x = bfu(acc[ms][ns][0] + bia);
        pk.y = bfu(acc[ms][ns][1] + bia);
        pk.z = bfu(acc[ms][ns][2] + bia);
        pk.w = bfu(acc[ms][ns][3] + bia);
        *(ushort4*)(vT + (size_t)((bb * 8 + hh) * 128 + d) * 2048 + s) = pk;
      }
    }
  }
}

// ---------------- fused attention (r13 champion: LDS-shared K/V, 64q block, 2 blocks/CU) --
// grid 512 = 16 (b,h) x 32 q-blocks of 64 rows; 256 threads = 4 waves; wave w owns q rows
// [q0+w*16,+16) and iterates ALL 2048 kv. Per 32-kv chunk the BLOCK stages K(8KB)+V(8KB)
// via global_load_lds (2 insts each per lane), double-buffered. 2 independent blocks/CU.
// K staged with XOR swizzle slot^=(row&7) via pre-swizzled global source; sweep 1 computes
// sums + PV (stash transpose) -> normalized O; sweep 2 recomputes QK^T from staged K,
// scales by 1/sum, NT-stores normalized attn.
__global__ __launch_bounds__(256, 2) void k_attn(
    const bf16* __restrict__ qT, const bf16* __restrict__ kT,
    const bf16* __restrict__ vT, const unsigned char* __restrict__ mask8,
    float* __restrict__ attn_out, bf16* __restrict__ Oc) {
  __shared__ __align__(16) char kbuf[2][8192];
  __shared__ __align__(16) char vbuf[2][8192];
  __shared__ __align__(16) char stash[4][1024];
  __shared__ float red2[64];

  // XCD-aware bijective swizzle: XCD x gets 64 consecutive works = exactly 2 (b,h) pairs.
  const int lbid = blockIdx.x;
  const int work = ((lbid & 7) << 6) + (lbid >> 3);
  const int bh = work >> 5;
  const int q0 = (work & 31) << 6;
  const int b = bh >> 3, h = bh & 7;
  const int tid = threadIdx.x;
  const int w = tid >> 6, lane = tid & 63, lo = lane & 15, hi = lane >> 4;

  const bf16* Qh = qT + (size_t)bh * SQ * HD;
  const bf16* Kh = kT + (size_t)bh * SQ * HD;
  const bf16* Vh = vT + (size_t)bh * HD * SQ;
  const int qg = q0 + w * 16 + lo;           // this lane's q row (col of swapped QK^T)

  // staging source addresses (chunk-invariant part), 2 gload_lds16 per lane for K and V.
  // K phys LDS (row,s) holds logical slot s^(row&7) -> lane fetches that slot.
  const int krow0 = (w << 2) + (lane >> 4);
  const int krow1 = 16 + krow0;
  const bf16* kg0 = Kh + (size_t)krow0 * HD + (((lane & 15) ^ (krow0 & 7)) << 3);
  const bf16* kg1 = Kh + (size_t)krow1 * HD + (((lane & 15) ^ (krow1 & 7)) << 3);
  // V linear: vbuf row = d (0..127), 64B of 32 kv per row.
  const int vrow0 = (w << 4) + (lane >> 2);
  const int vrow1 = 64 + vrow0;
  const bf16* vg0 = Vh + (size_t)vrow0 * SQ + ((lane & 3) << 3);
  const bf16* vg1 = Vh + (size_t)vrow1 * SQ + ((lane & 3) << 3);

  bf16x8 qf[4];                              // 16 q rows (pre-scaled by 1/sqrt(D))
#pragma unroll
  for (int ks = 0; ks < 4; ++ks)
    qf[ks] = ld8(Qh + (size_t)qg * HD + ks * 32 + hi * 8);

  const f32x4 z4 = {0.f, 0.f, 0.f, 0.f};
  f32x4 acc[8];
#pragma unroll
  for (int ds = 0; ds < 8; ++ds) acc[ds] = z4;
  float ssum = 0.f;

  // ======== sweep 1: sums + PV ========
  gload_lds16(kg0, &kbuf[0][w * 1024]);
  gload_lds16(kg1, &kbuf[0][4096 + w * 1024]);
  gload_lds16(vg0, &vbuf[0][w * 1024]);
  gload_lds16(vg1, &vbuf[0][4096 + w * 1024]);
  __syncthreads();

  for (int i = 0; i < 64; ++i) {
    const int kvA = i << 5;
    const int cur = i & 1;
    if (i < 63) {
      const size_t ko = (size_t)(kvA + 32) * HD;
      gload_lds16(kg0 + ko, &kbuf[cur ^ 1][w * 1024]);
      gload_lds16(kg1 + ko, &kbuf[cur ^ 1][4096 + w * 1024]);
      gload_lds16(vg0 + (kvA + 32), &vbuf[cur ^ 1][w * 1024]);
      gload_lds16(vg1 + (kvA + 32), &vbuf[cur ^ 1][4096 + w * 1024]);
    }
    const char* kb = kbuf[cur];
    const char* vb = vbuf[cur];
#pragma unroll
    for (int t = 0; t < 2; ++t) {
      const int row = t * 16 + lo;
      bf16x8 af[4];
#pragma unroll
      for (int ks = 0; ks < 4; ++ks)
        af[ks] = *(const bf16x8*)(kb + row * 256 + ((((ks << 2) + hi)) ^ (row & 7)) * 16);
      f32x4 c = z4;
#pragma unroll
      for (int ks = 0; ks < 4; ++ks) c = mfma16(af[ks], qf[ks], c);
      const unsigned mu = *(const unsigned*)(mask8 + (size_t)qg * SQ + kvA + t * 16 + hi * 4);
      // exp(c*(0.5+0.5m)) = exp2(c * fma(m, L2EH, L2EH))
      float p0 = exp2f(c[0] * fmaf((float)(mu & 0xff),         L2EH, L2EH));
      float p1 = exp2f(c[1] * fmaf((float)((mu >> 8) & 0xff),  L2EH, L2EH));
      float p2 = exp2f(c[2] * fmaf((float)((mu >> 16) & 0xff), L2EH, L2EH));
      float p3 = exp2f(c[3] * fmaf((float)((mu >> 24) & 0xff), L2EH, L2EH));
      ssum += (p0 + p1) + (p2 + p3);
      *(uint2*)(stash[w] + lo * 64 + ((t * 32 + hi * 8) ^ ((lo & 3) << 4))) =
          make_uint2(packbf2(p0, p1), packbf2(p2, p3));
    }
    // PV over these 32 kv (same-wave stash readback)
    bf16x8 pa = *(const bf16x8*)(stash[w] + lo * 64 + ((hi * 16) ^ ((lo & 3) << 4)));
#pragma unroll
    for (int ds = 0; ds < 8; ++ds) {
      bf16x8 vf = *(const bf16x8*)(vb + (ds * 16 + lo) * 64 + hi * 16);
      acc[ds] = mfma16(pa, vf, acc[ds]);
    }
    __syncthreads();
  }

  // row sums complete per wave (wave saw full kv): reduce over hi, publish 1/sum
  ssum += __shfl_xor(ssum, 16);
  ssum += __shfl_xor(ssum, 32);
  if (hi == 0) red2[w * 16 + lo] = 1.0f / ssum;
  __syncthreads();

  // O write: normalized, direct from regs (no cross-wave reduce needed)
#pragma unroll
  for (int ds = 0; ds < 8; ++ds)
#pragma unroll
    for (int r = 0; r < 4; ++r) {
      const int qrow = w * 16 + hi * 4 + r;
      Oc[(size_t)(b * SQ + q0 + qrow) * (NH * HD) + h * HD + ds * 16 + lo] =
          (bf16)(acc[ds][r] * red2[qrow]);
    }

  // ======== sweep 2: recompute QK^T from staged K, write normalized attn ========
  const float rinv = red2[w * 16 + lo];
  float* abase = attn_out + (size_t)bh * SQ * SQ + (size_t)qg * SQ;
  gload_lds16(kg0, &kbuf[0][w * 1024]);
  gload_lds16(kg1, &kbuf[0][4096 + w * 1024]);
  __syncthreads();
  for (int i = 0; i < 64; ++i) {
    const int kvA = i << 5;
    const int cur = i & 1;
    if (i < 63) {
      const size_t ko = (size_t)(kvA + 32) * HD;
      gload_lds16(kg0 + ko, &kbuf[cur ^ 1][w * 1024]);
      gload_lds16(kg1 + ko, &kbuf[cur ^ 1][4096 + w * 1024]);
    }
    const char* kb = kbuf[cur];
#pragma unroll
    for (int t = 0; t < 2; ++t) {
      const int row = t * 16 + lo;
      bf16x8 af[4];
#pragma unroll
      for (int ks = 0; ks < 4; ++ks)
        af[ks] = *(const bf16x8*)(kb + row * 256 + ((((ks << 2) + hi)) ^ (row & 7)) * 16);
      f32x4 c = z4;
#pragma unroll
      for (int ks = 0; ks < 4; ++ks) c = mfma16(af[ks], qf[ks], c);
      const unsigned mu = *(const unsigned*)(mask8 + (size_t)qg * SQ + kvA + t * 16 + hi * 4);
      f32x4 o;
      o[0] = exp2f(c[0] * fmaf((float)(mu & 0xff),         L2EH, L2EH)) * rinv;
      o[1] = exp2f(c[1] * fmaf((float)((mu >> 8) & 0xff),  L2EH, L2EH)) * rinv;
      o[2] = exp2f(c[2] * fmaf((float)((mu >> 16) & 0xff), L2EH, L2EH)) * rinv;
      o[3] = exp2f(c[3] * fmaf((float)((mu >> 24) & 0xff), L2EH, L2EH)) * rinv;
      __builtin_nontemporal_store(o, (f32x4*)(abase + kvA + t * 16 + hi * 4));
    }
    __syncthreads();
  }
}

// ---------------- out@Wo + bo + x -> LayerNorm1 -> h (f32 + bf16) ----------------
__global__ __launch_bounds__(256, 4) void k_owo(
    const bf16* __restrict__ Oc, const bf16* __restrict__ WoT,
    const float* __restrict__ bo, const float* __restrict__ x,
    const float* __restrict__ g1, const float* __restrict__ be1,
    float* __restrict__ hf, bf16* __restrict__ hb) {
  __shared__ __align__(16) float hbuf[16 * 128];
  const int m0 = blockIdx.x * 16;
  const int tid = threadIdx.x;
  const int w = tid >> 6, lane = tid & 63, lo = lane & 15, hi = lane >> 4;
  const int nw = w * 32;
  const f32x4 z4 = {0.f, 0.f, 0.f, 0.f};
  f32x4 acc[2] = {z4, z4};
#pragma unroll 4
  for (int kk = 0; kk < 32; ++kk) {
    bf16x8 a = ld8(Oc + (size_t)(m0 + lo) * 1024 + kk * 32 + hi * 8);
#pragma unroll
    for (int ns = 0; ns < 2; ++ns) {
      bf16x8 bb = ld8(WoT + (size_t)(nw + ns * 16 + lo) * 1024 + kk * 32 + hi * 8);
      acc[ns] = mfma16(a, bb, acc[ns]);
    }
  }
#pragma unroll
  for (int ns = 0; ns < 2; ++ns) {
    const int n = nw + ns * 16 + lo;
    const float bia = bo[n];
#pragma unroll
    for (int r = 0; r < 4; ++r) {
      const int mr = hi * 4 + r;
      hbuf[mr * 128 + n] = acc[ns][r] + bia + x[(size_t)(m0 + mr) * 128 + n];
    }
  }
  __syncthreads();
  const float2 g = *(const float2*)(g1 + lane * 2);
  const float2 be = *(const float2*)(be1 + lane * 2);
#pragma unroll
  for (int rr = 0; rr < 4; ++rr) {
    const int row = w * 4 + rr;
    float2 v = *(float2*)&hbuf[row * 128 + lane * 2];
    float s = v.x + v.y, sq = v.x * v.x + v.y * v.y;
#pragma unroll
    for (int off = 32; off; off >>= 1) { s += __shfl_xor(s, off); sq += __shfl_xor(sq, off); }
    const float mean = s * (1.f / 128.f);
    const float var = sq * (1.f / 128.f) - mean * mean;
    const float rstd = rsqrtf(var + 1e-5f);
    const float y0 = (v.x - mean) * rstd * g.x + be.x;
    const float y1 = (v.y - mean) * rstd * g.y + be.y;
    const size_t o = (size_t)(m0 + row) * 128 + lane * 2;
    *(float2*)(hf + o) = make_float2(y0, y1);
    *(unsigned*)(hb + o) = packbf2(y0, y1);
  }
}

// ---------------- FFN (relu(h@W1+b1)@W2+b2) + residual -> LayerNorm2 -> y ----------------
__global__ __launch_bounds__(256, 4) void k_ffn(
    const bf16* __restrict__ hb, const float* __restrict__ hf,
    const bf16* __restrict__ W1T, const bf16* __restrict__ W2T,
    const float* __restrict__ b1, const float* __restrict__ b2,
    const float* __restrict__ g2, const float* __restrict__ be2,
    float* __restrict__ yout) {
  __shared__ __align__(16) bf16 s1[16 * 136];   // +8 pad per row: conflict-free b128 rereads
  __shared__ __align__(16) float ybuf[16 * 128];
  const int m0 = blockIdx.x * 16;
  const int tid = threadIdx.x;
  const int w = tid >> 6, lane = tid & 63, lo = lane & 15, hi = lane >> 4;
  const int nw = w * 32;
  const f32x4 z4 = {0.f, 0.f, 0.f, 0.f};
  f32x4 a1[2] = {z4, z4};
#pragma unroll
  for (int kk = 0; kk < 4; ++kk) {
    bf16x8 a = ld8(hb + (size_t)(m0 + lo) * 128 + kk * 32 + hi * 8);
#pragma unroll
    for (int ns = 0; ns < 2; ++ns)
      a1[ns] = mfma16(a, ld8(W1T + (size_t)(nw + ns * 16 + lo) * 128 + kk * 32 + hi * 8), a1[ns]);
  }
#pragma unroll
  for (int ns = 0; ns < 2; ++ns) {
    const int n = nw + ns * 16 + lo;
    const float bia = b1[n];
#pragma unroll
    for (int r = 0; r < 4; ++r)
      s1[(hi * 4 + r) * 136 + n] = (bf16)fmaxf(a1[ns][r] + bia, 0.f);
  }
  __syncthreads();
  f32x4 a2[2] = {z4, z4};
#pragma unroll
  for (int kk = 0; kk < 4; ++kk) {
    bf16x8 a = *(const bf16x8*)&s1[lo * 136 + kk * 32 + hi * 8];
#pragma unroll
    for (int ns = 0; ns < 2; ++ns)
      a2[ns] = mfma16(a, ld8(W2T + (size_t)(nw + ns * 16 + lo) * 128 + kk * 32 + hi * 8), a2[ns]);
  }
#pragma unroll
  for (int ns = 0; ns < 2; ++ns) {
    const int n = nw + ns * 16 + lo;
    const float bia = b2[n];
#pragma unroll
    for (int r = 0; r < 4; ++r) {
      const int mr = hi * 4 + r;
      ybuf[mr * 128 + n] = a2[ns][r] + bia + hf[(size_t)(m0 + mr) * 128 + n];
    }
  }
  __syncthreads();
  const float2 g = *(const float2*)(g2 + lane * 2);
  const float2 be = *(const float2*)(be2 + lane * 2);
#pragma unroll
  for (int rr = 0; rr < 4; ++rr) {
    const int row = w * 4 + rr;
    float2 v = *(float2*)&ybuf[row * 128 + lane * 2];
    float s = v.x + v.y, sq = v.x * v.x + v.y * v.y;
#pragma unroll
    for (int off = 32; off; off >>= 1) { s += __shfl_xor(s, off); sq += __shfl_xor(sq, off); }
    const float mean = s * (1.f / 128.f);
    const float var = sq * (1.f / 128.f) - mean * mean;
    const float rstd = rsqrtf(var + 1e-5f);
    const float y0 = (v.x - mean) * rstd * g.x + be.x;
    const float y1 = (v.y - mean) * rstd * g.y + be.y;
    *(float2*)(yout + (size_t)(m0 + row) * 128 + lane * 2) = make_float2(y0, y1);
  }
}

extern "C" void kernel_launch(void* const* d_in, const int* in_sizes, int n_in,
                              void* d_out, int out_size, void* d_ws, size_t ws_size,
                              hipStream_t stream) {
  const float* x  = (const float*)d_in[0];
  const int* adj  = (const int*)d_in[1];
  const float* Wq = (const float*)d_in[2];  const float* bq = (const float*)d_in[3];
  const float* Wk = (const float*)d_in[4];  const float* bk = (const float*)d_in[5];
  const float* Wv = (const float*)d_in[6];  const float* bv = (const float*)d_in[7];
  const float* Wo = (const float*)d_in[8];  const float* bo = (const float*)d_in[9];
  const float* g1 = (const float*)d_in[10]; const float* be1 = (const float*)d_in[11];
  const float* g2 = (const float*)d_in[12]; const float* be2 = (const float*)d_in[13];
  const float* W1 = (const float*)d_in[14]; const float* b1 = (const float*)d_in[15];
  const float* W2 = (const float*)d_in[16]; const float* b2 = (const float*)d_in[17];

  char* ws = (char*)d_ws;
  bf16* xb     = (bf16*)(ws + 0);
  bf16* WqkvT  = (bf16*)(ws + 1048576);
  bf16* WoT    = (bf16*)(ws + 1835008);
  bf16* W1T    = (bf16*)(ws + 2097152);
  bf16* W2T    = (bf16*)(ws + 2129920);
  unsigned char* mask8 = (unsigned char*)(ws + 2162688);
  bf16* qT     = (bf16*)(ws + 6356992);
  bf16* kT     = (bf16*)(ws + 14745600);
  bf16* vT     = (bf16*)(ws + 23134208);
  bf16* Oc     = (bf16*)(ws + 31522816);
  float* hf    = (float*)(ws + 39911424);
  bf16* hb     = (bf16*)(ws + 42008576);

  float* yout = (float*)d_out;
  float* attn_out = yout + (size_t)NROWS * HD;  // y first (524288 f32), then attn

  k_prep_a<<<6144, 256, 0, stream>>>(x, adj, xb, mask8);
  k_prep_w<<<2176, 256, 0, stream>>>(Wq, Wk, Wv, Wo, W1, W2, WqkvT, WoT, W1T, W2T);
  k_qkv<<<3072, 256, 0, stream>>>(xb, WqkvT, bq, bk, bv, qT, kT, vT);
  k_attn<<<512, 256, 0, stream>>>(qT, kT, vT, mask8, attn_out, Oc);
  k_owo<<<256, 256, 0, stream>>>(Oc, WoT, bo, x, g1, be1, hf, hb);
  k_ffn<<<256, 256, 0, stream>>>(hb, hf, W1T, W2T, b1, b2, g2, be2, yout);
}